// Round 4
// baseline (213.000 us; speedup 1.0000x reference)
//
#include <hip/hip_runtime.h>
#include <math.h>

// Problem constants (match reference setup_inputs)
#define Bn 4096
#define Sn 2048
#define BLOCK 256
#define CHUNK (Sn / BLOCK)       // 8 steps per thread
#define NM (Bn * BLOCK)          // total chunk matrices = 1,048,576

// =====================================================================
// Kernel 1: pure streaming. One block per batch element; each thread
// composes an 8-step chunk transfer matrix (linear domain) + gold partial
// and stores (m00,m01),(m10,m11),(L,gold) to SoA float2 workspace.
// No shuffles, no reduction tail -> waves retire fast, block churn keeps
// memory pipeline full.
// =====================================================================
__global__ __launch_bounds__(BLOCK) void crf_chunk(
    const float* __restrict__ emissions,     // [B, S, 2]
    const float* __restrict__ trans_params,  // [4, 2, 2]
    const int*   __restrict__ tags,          // [B, S]
    const int*   __restrict__ who2who,       // [B, S]
    const int*   __restrict__ intime,        // [B, S]
    const int*   __restrict__ distance,      // [B, S]
    float2*      __restrict__ wsA,           // [NM] (m00,m01)
    float2*      __restrict__ wsB,           // [NM] (m10,m11)
    float2*      __restrict__ wsC)           // [NM] (L, gold)
{
    const int b = blockIdx.x;
    const int c = threadIdx.x;               // chunk index within sequence
    const long base = (long)b * Sn;
    const int s0 = c * CHUNK;

    // sel banks: [sel][i][j] at [sel*4 + i*2 + j]; sel==0 is zero/ones
    __shared__ __align__(16) float lbank[20];  // log-domain (gold path)
    __shared__ __align__(16) float ebank[20];  // exp(trans)  (forward scan)

    // ---- issue all global loads ----
    const int4* tp = (const int4*)(tags     + base) + c * 2;
    const int4* wp = (const int4*)(who2who  + base) + c * 2;
    const int4* ip = (const int4*)(intime   + base) + c * 2;
    const int4* dp = (const int4*)(distance + base) + c * 2;
    const float4* ep = (const float4*)(emissions + base * 2) + c * 4;

    float4 e0 = ep[0], e1 = ep[1], e2 = ep[2], e3 = ep[3];
    int4 ta = tp[0], tb = tp[1];
    int4 wa = wp[0], wb = wp[1];
    int4 ia = ip[0], ib = ip[1];
    int4 da = dp[0], db = dp[1];
    int prev_tag = (c > 0) ? tags[base + s0 - 1] : 0;

    if (c < 20) {
        float v = (c < 4) ? 0.0f : trans_params[c - 4];
        lbank[c] = v;
        ebank[c] = __expf(v);    // sel 0 -> all-ones matrix
    }
    __syncthreads();

    int wv[CHUNK]   = {wa.x, wa.y, wa.z, wa.w, wb.x, wb.y, wb.z, wb.w};
    int iv[CHUNK]   = {ia.x, ia.y, ia.z, ia.w, ib.x, ib.y, ib.z, ib.w};
    int dv[CHUNK]   = {da.x, da.y, da.z, da.w, db.x, db.y, db.z, db.w};
    int tagv[CHUNK] = {ta.x, ta.y, ta.z, ta.w, tb.x, tb.y, tb.z, tb.w};
    float emv[CHUNK][2] = {
        {e0.x, e0.y}, {e0.z, e0.w}, {e1.x, e1.y}, {e1.z, e1.w},
        {e2.x, e2.y}, {e2.z, e2.w}, {e3.x, e3.y}, {e3.z, e3.w}};

    int sel[CHUNK];
    #pragma unroll
    for (int k = 0; k < CHUNK; ++k) {
        int w = wv[k], it = iv[k], d = dv[k];
        sel[k] = (w == -1) ? 0 : (w == 1) ? 1 : (it == 0) ? 2 : (d == 0) ? 3 : 4;
    }

    // ---- linear-domain chunk scan (validated R2/R3: absmax 8.0) ----
    // Worst-case per-step growth ~1500x; 8 steps < 3e25 -- fp32 safe.
    float4 P0 = *(const float4*)(ebank + sel[0] * 4);
    float m00 = P0.x * __expf(emv[0][0]), m01 = P0.y * __expf(emv[0][1]);
    float m10 = P0.z * __expf(emv[0][0]), m11 = P0.w * __expf(emv[0][1]);
    #pragma unroll
    for (int k = 1; k < CHUNK; ++k) {
        float4 P = *(const float4*)(ebank + sel[k] * 4);
        float x0 = __expf(emv[k][0]), x1 = __expf(emv[k][1]);
        float n00 = fmaf(m00, P.x, m01 * P.z) * x0;
        float n01 = fmaf(m00, P.y, m01 * P.w) * x1;
        float n10 = fmaf(m10, P.x, m11 * P.z) * x0;
        float n11 = fmaf(m10, P.y, m11 * P.w) * x1;
        m00 = n00; m01 = n01; m10 = n10; m11 = n11;
    }

    // gold path (log domain)
    float gold = 0.0f;
    #pragma unroll
    for (int k = 0; k < CHUNK; ++k) {
        int tg = tagv[k];
        gold += tg ? emv[k][1] : emv[k][0];
        if (k > 0 || c > 0) {               // no transition at global s==0
            int pt = (k == 0) ? prev_tag : tagv[k - 1];
            gold += lbank[(sel[k] << 2) + (pt << 1) + tg];
        }
    }

    // normalize; carry scale in log space
    float mx  = fmaxf(fmaxf(m00, m01), fmaxf(m10, m11));
    float inv = 1.0f / mx;
    float L   = __logf(mx);

    const int gid = b * BLOCK + c;
    wsA[gid] = make_float2(m00 * inv, m01 * inv);
    wsB[gid] = make_float2(m10 * inv, m11 * inv);
    wsC[gid] = make_float2(L, gold);
}

// =====================================================================
// Kernel 2: reduction. One wave per batch element (4 waves/block).
// Each lane loads 4 consecutive chunk matrices (coalesced float4),
// composes them serially, then a 6-round order-preserving xor-shuffle
// butterfly with per-round renormalization.
// =====================================================================
__global__ __launch_bounds__(BLOCK) void crf_reduce(
    const float2* __restrict__ wsA,
    const float2* __restrict__ wsB,
    const float2* __restrict__ wsC,
    float*        __restrict__ out)          // [2, B]
{
    const int lane = threadIdx.x & 63;
    const int wave = threadIdx.x >> 6;
    const int b = blockIdx.x * 4 + wave;

    // this lane's 4 chunks: c0 = lane*4 .. lane*4+3
    const int idx4 = b * (BLOCK / 2) + lane * 2;     // float4 index into pairs
    const float4* A4 = (const float4*)wsA;
    const float4* B4 = (const float4*)wsB;
    const float4* C4 = (const float4*)wsC;
    float4 a0 = A4[idx4], a1 = A4[idx4 + 1];   // (m00,m01) of c..c+1, c+2..c+3
    float4 b0 = B4[idx4], b1 = B4[idx4 + 1];   // (m10,m11)
    float4 c0 = C4[idx4], c1 = C4[idx4 + 1];   // (L,gold)

    // serial in-order compose of the 4 chunks
    float m00 = a0.x, m01 = a0.y, m10 = b0.x, m11 = b0.y;
    float L = c0.x, gold = c0.y;
    {
        float q00[3] = {a0.z, a1.x, a1.z};
        float q01[3] = {a0.w, a1.y, a1.w};
        float q10[3] = {b0.z, b1.x, b1.z};
        float q11[3] = {b0.w, b1.y, b1.w};
        float qL[3]  = {c0.z, c1.x, c1.z};
        float qg[3]  = {c0.w, c1.y, c1.w};
        #pragma unroll
        for (int q = 0; q < 3; ++q) {
            float n00 = fmaf(m00, q00[q], m01 * q10[q]);
            float n01 = fmaf(m00, q01[q], m01 * q11[q]);
            float n10 = fmaf(m10, q00[q], m11 * q10[q]);
            float n11 = fmaf(m10, q01[q], m11 * q11[q]);
            m00 = n00; m01 = n01; m10 = n10; m11 = n11;
            L += qL[q]; gold += qg[q];
        }
        float mx  = fmaxf(fmaxf(m00, m01), fmaxf(m10, m11));
        float inv = 1.0f / mx;
        L += __logf(mx);
        m00 *= inv; m01 *= inv; m10 *= inv; m11 *= inv;
    }

    // order-preserving butterfly with per-round renorm
    #pragma unroll
    for (int m = 1; m < 64; m <<= 1) {
        float o00 = __shfl_xor(m00, m);
        float o01 = __shfl_xor(m01, m);
        float o10 = __shfl_xor(m10, m);
        float o11 = __shfl_xor(m11, m);
        float oL  = __shfl_xor(L, m);
        float og  = __shfl_xor(gold, m);
        bool up = (lane & m) != 0;
        float x00 = up ? o00 : m00, x01 = up ? o01 : m01;
        float x10 = up ? o10 : m10, x11 = up ? o11 : m11;
        float y00 = up ? m00 : o00, y01 = up ? m01 : o01;
        float y10 = up ? m10 : o10, y11 = up ? m11 : o11;
        m00 = fmaf(x00, y00, x01 * y10);
        m01 = fmaf(x00, y01, x01 * y11);
        m10 = fmaf(x10, y00, x11 * y10);
        m11 = fmaf(x10, y01, x11 * y11);
        L += oL;
        gold += og;
        float mx  = fmaxf(fmaxf(m00, m01), fmaxf(m10, m11));
        float inv = 1.0f / mx;
        L += __logf(mx);
        m00 *= inv; m01 *= inv; m10 *= inv; m11 *= inv;
    }

    if (lane == 0) {
        float tot = L + __logf(m00 + m01 + m10 + m11);
        out[b]      = gold;   // gold_score
        out[Bn + b] = tot;    // total_score
    }
}

extern "C" void kernel_launch(void* const* d_in, const int* in_sizes, int n_in,
                              void* d_out, int out_size, void* d_ws, size_t ws_size,
                              hipStream_t stream) {
    const float* emissions    = (const float*)d_in[0];
    const float* trans_params = (const float*)d_in[1];
    const int*   tags         = (const int*)d_in[2];
    const int*   who2who      = (const int*)d_in[3];
    const int*   intime       = (const int*)d_in[4];
    const int*   distance     = (const int*)d_in[5];
    float* out = (float*)d_out;

    float2* wsA = (float2*)d_ws;           // 8 MB
    float2* wsB = wsA + NM;                // 8 MB
    float2* wsC = wsB + NM;                // 8 MB   (24 MB total)

    crf_chunk<<<dim3(Bn), dim3(BLOCK), 0, stream>>>(
        emissions, trans_params, tags, who2who, intime, distance,
        wsA, wsB, wsC);
    crf_reduce<<<dim3(Bn / 4), dim3(BLOCK), 0, stream>>>(
        wsA, wsB, wsC, out);
}

// Round 5
// 209.921 us; speedup vs baseline: 1.0147x; 1.0147x over previous
//
#include <hip/hip_runtime.h>
#include <math.h>

// Problem constants (match reference setup_inputs)
#define Bn 4096
#define Sn 2048
#define BLOCK 256
#define CHUNK (Sn / BLOCK)       // 8 steps per thread
#define NM (Bn * BLOCK)          // total chunk matrices = 1,048,576

// ---- global_load_lds wrapper (gfx950: width 16 = global_load_lds_dwordx4)
// Per-lane global address; LDS dest = wave-uniform base + lane*16.
typedef __attribute__((address_space(3))) void  lds_void;
typedef const __attribute__((address_space(1))) void g_void;
__device__ __forceinline__ void load_lds16(const void* g, void* l) {
    __builtin_amdgcn_global_load_lds((g_void*)g, (lds_void*)l, 16, 0, 0);
}

// =====================================================================
// Kernel 1: streaming via direct-to-LDS DMA.
// R4 post-mortem: VGPR-destination loads are compiler-batched (VGPR=36
// regardless of launch_bounds) -> ~2-5 KB/CU in flight -> 1.5 TB/s cap.
// global_load_lds holds no destination VGPRs: each wave fires 12 x 1KB
// DMAs, drains once at the barrier.
// Staging permutation: for a P-phase array (P = blocks per thread),
//   LDS slot [w*64P + j*64 + l]  <-  global 16B-block [64P*w + P*l + j]
// so consumer phase-j reads are lane-stride-16B (conflict-free b128).
// =====================================================================
__global__ __launch_bounds__(BLOCK) void crf_chunk(
    const float* __restrict__ emissions,     // [B, S, 2]
    const float* __restrict__ trans_params,  // [4, 2, 2]
    const int*   __restrict__ tags,          // [B, S]
    const int*   __restrict__ who2who,       // [B, S]
    const int*   __restrict__ intime,        // [B, S]
    const int*   __restrict__ distance,      // [B, S]
    float2*      __restrict__ wsA,           // [NM] (m00,m01)
    float2*      __restrict__ wsB,           // [NM] (m10,m11)
    float2*      __restrict__ wsC)           // [NM] (L, gold)
{
    const int b = blockIdx.x;
    const int t = threadIdx.x;               // chunk index within sequence
    const int w = t >> 6, l = t & 63;

    __shared__ __align__(16) float s_em[Sn * 2];   // 16 KB (swizzled)
    __shared__ __align__(16) int   s_tg[Sn];       // 8 KB each (swizzled)
    __shared__ __align__(16) int   s_wh[Sn];
    __shared__ __align__(16) int   s_it[Sn];
    __shared__ __align__(16) int   s_ds[Sn];
    __shared__ __align__(16) float lbank[20];      // log-domain (gold)
    __shared__ __align__(16) float ebank[20];      // exp(trans) (scan)

    // ---- stage: 12 DMA call sites, all fire-and-forget ----
    const char* emg = (const char*)(emissions + (long)b * Sn * 2);
    const char* tgg = (const char*)(tags     + (long)b * Sn);
    const char* whg = (const char*)(who2who  + (long)b * Sn);
    const char* itg = (const char*)(intime   + (long)b * Sn);
    const char* dsg = (const char*)(distance + (long)b * Sn);

    // emissions: 4 phases (4 blocks of 16B per thread)
    #pragma unroll
    for (int j = 0; j < 4; ++j)
        load_lds16(emg + t * 64 + j * 16,
                   (char*)s_em + w * 4096 + j * 1024);
    // int arrays: 2 phases each
    #pragma unroll
    for (int j = 0; j < 2; ++j) {
        load_lds16(tgg + t * 32 + j * 16, (char*)s_tg + w * 2048 + j * 1024);
        load_lds16(whg + t * 32 + j * 16, (char*)s_wh + w * 2048 + j * 1024);
        load_lds16(itg + t * 32 + j * 16, (char*)s_it + w * 2048 + j * 1024);
        load_lds16(dsg + t * 32 + j * 16, (char*)s_ds + w * 2048 + j * 1024);
    }

    if (t < 20) {
        float v = (t < 4) ? 0.0f : trans_params[t - 4];
        lbank[t] = v;
        ebank[t] = __expf(v);    // sel 0 -> all-ones matrix
    }
    __syncthreads();   // drains vmcnt(0): all DMAs landed

    // ---- consumer reads: lane-stride-16B b128s (conflict-free) ----
    const float4* em4 = (const float4*)s_em;
    float4 e0 = em4[w * 256 +   0 + l];   // global em block 4c+0
    float4 e1 = em4[w * 256 +  64 + l];   // 4c+1
    float4 e2 = em4[w * 256 + 128 + l];   // 4c+2
    float4 e3 = em4[w * 256 + 192 + l];   // 4c+3

    const int4* tg4 = (const int4*)s_tg;
    const int4* wh4 = (const int4*)s_wh;
    const int4* it4 = (const int4*)s_it;
    const int4* ds4 = (const int4*)s_ds;
    int4 ta = tg4[w * 128 +      l], tb = tg4[w * 128 + 64 + l];
    int4 wa = wh4[w * 128 +      l], wb = wh4[w * 128 + 64 + l];
    int4 ia = it4[w * 128 +      l], ib = it4[w * 128 + 64 + l];
    int4 da = ds4[w * 128 +      l], db = ds4[w * 128 + 64 + l];

    // prev_tag = tags[8t-1]: global int-block g=2t-1 (odd -> phase 1)
    int prev_tag = 0;
    if (t > 0) {
        int g  = 2 * t - 1;
        int wp = g >> 7, lp = (g & 127) >> 1;
        prev_tag = s_tg[(wp * 128 + 64 + lp) * 4 + 3];
    }

    int wv[CHUNK]   = {wa.x, wa.y, wa.z, wa.w, wb.x, wb.y, wb.z, wb.w};
    int iv[CHUNK]   = {ia.x, ia.y, ia.z, ia.w, ib.x, ib.y, ib.z, ib.w};
    int dv[CHUNK]   = {da.x, da.y, da.z, da.w, db.x, db.y, db.z, db.w};
    int tagv[CHUNK] = {ta.x, ta.y, ta.z, ta.w, tb.x, tb.y, tb.z, tb.w};
    float emv[CHUNK][2] = {
        {e0.x, e0.y}, {e0.z, e0.w}, {e1.x, e1.y}, {e1.z, e1.w},
        {e2.x, e2.y}, {e2.z, e2.w}, {e3.x, e3.y}, {e3.z, e3.w}};

    int sel[CHUNK];
    #pragma unroll
    for (int k = 0; k < CHUNK; ++k) {
        int ww = wv[k], it = iv[k], d = dv[k];
        sel[k] = (ww == -1) ? 0 : (ww == 1) ? 1 : (it == 0) ? 2 : (d == 0) ? 3 : 4;
    }

    // ---- linear-domain chunk scan (validated R2-R4: absmax 8.0) ----
    float4 P0 = *(const float4*)(ebank + sel[0] * 4);
    float m00 = P0.x * __expf(emv[0][0]), m01 = P0.y * __expf(emv[0][1]);
    float m10 = P0.z * __expf(emv[0][0]), m11 = P0.w * __expf(emv[0][1]);
    #pragma unroll
    for (int k = 1; k < CHUNK; ++k) {
        float4 P = *(const float4*)(ebank + sel[k] * 4);
        float x0 = __expf(emv[k][0]), x1 = __expf(emv[k][1]);
        float n00 = fmaf(m00, P.x, m01 * P.z) * x0;
        float n01 = fmaf(m00, P.y, m01 * P.w) * x1;
        float n10 = fmaf(m10, P.x, m11 * P.z) * x0;
        float n11 = fmaf(m10, P.y, m11 * P.w) * x1;
        m00 = n00; m01 = n01; m10 = n10; m11 = n11;
    }

    // gold path (log domain)
    float gold = 0.0f;
    #pragma unroll
    for (int k = 0; k < CHUNK; ++k) {
        int tg = tagv[k];
        gold += tg ? emv[k][1] : emv[k][0];
        if (k > 0 || t > 0) {               // no transition at global s==0
            int pt = (k == 0) ? prev_tag : tagv[k - 1];
            gold += lbank[(sel[k] << 2) + (pt << 1) + tg];
        }
    }

    // normalize; carry scale in log space
    float mx  = fmaxf(fmaxf(m00, m01), fmaxf(m10, m11));
    float inv = 1.0f / mx;
    float L   = __logf(mx);

    const int gid = b * BLOCK + t;
    wsA[gid] = make_float2(m00 * inv, m01 * inv);
    wsB[gid] = make_float2(m10 * inv, m11 * inv);
    wsC[gid] = make_float2(L, gold);
}

// =====================================================================
// Kernel 2: reduction. One wave per batch element (4 waves/block).
// =====================================================================
__global__ __launch_bounds__(BLOCK) void crf_reduce(
    const float2* __restrict__ wsA,
    const float2* __restrict__ wsB,
    const float2* __restrict__ wsC,
    float*        __restrict__ out)          // [2, B]
{
    const int lane = threadIdx.x & 63;
    const int wave = threadIdx.x >> 6;
    const int b = blockIdx.x * 4 + wave;

    const int idx4 = b * (BLOCK / 2) + lane * 2;     // float4 index into pairs
    const float4* A4 = (const float4*)wsA;
    const float4* B4 = (const float4*)wsB;
    const float4* C4 = (const float4*)wsC;
    float4 a0 = A4[idx4], a1 = A4[idx4 + 1];
    float4 b0 = B4[idx4], b1 = B4[idx4 + 1];
    float4 c0 = C4[idx4], c1 = C4[idx4 + 1];

    float m00 = a0.x, m01 = a0.y, m10 = b0.x, m11 = b0.y;
    float L = c0.x, gold = c0.y;
    {
        float q00[3] = {a0.z, a1.x, a1.z};
        float q01[3] = {a0.w, a1.y, a1.w};
        float q10[3] = {b0.z, b1.x, b1.z};
        float q11[3] = {b0.w, b1.y, b1.w};
        float qL[3]  = {c0.z, c1.x, c1.z};
        float qg[3]  = {c0.w, c1.y, c1.w};
        #pragma unroll
        for (int q = 0; q < 3; ++q) {
            float n00 = fmaf(m00, q00[q], m01 * q10[q]);
            float n01 = fmaf(m00, q01[q], m01 * q11[q]);
            float n10 = fmaf(m10, q00[q], m11 * q10[q]);
            float n11 = fmaf(m10, q01[q], m11 * q11[q]);
            m00 = n00; m01 = n01; m10 = n10; m11 = n11;
            L += qL[q]; gold += qg[q];
        }
        float mx  = fmaxf(fmaxf(m00, m01), fmaxf(m10, m11));
        float inv = 1.0f / mx;
        L += __logf(mx);
        m00 *= inv; m01 *= inv; m10 *= inv; m11 *= inv;
    }

    #pragma unroll
    for (int m = 1; m < 64; m <<= 1) {
        float o00 = __shfl_xor(m00, m);
        float o01 = __shfl_xor(m01, m);
        float o10 = __shfl_xor(m10, m);
        float o11 = __shfl_xor(m11, m);
        float oL  = __shfl_xor(L, m);
        float og  = __shfl_xor(gold, m);
        bool up = (lane & m) != 0;
        float x00 = up ? o00 : m00, x01 = up ? o01 : m01;
        float x10 = up ? o10 : m10, x11 = up ? o11 : m11;
        float y00 = up ? m00 : o00, y01 = up ? m01 : o01;
        float y10 = up ? m10 : o10, y11 = up ? m11 : o11;
        m00 = fmaf(x00, y00, x01 * y10);
        m01 = fmaf(x00, y01, x01 * y11);
        m10 = fmaf(x10, y00, x11 * y10);
        m11 = fmaf(x10, y01, x11 * y11);
        L += oL;
        gold += og;
        float mx  = fmaxf(fmaxf(m00, m01), fmaxf(m10, m11));
        float inv = 1.0f / mx;
        L += __logf(mx);
        m00 *= inv; m01 *= inv; m10 *= inv; m11 *= inv;
    }

    if (lane == 0) {
        float tot = L + __logf(m00 + m01 + m10 + m11);
        out[b]      = gold;   // gold_score
        out[Bn + b] = tot;    // total_score
    }
}

extern "C" void kernel_launch(void* const* d_in, const int* in_sizes, int n_in,
                              void* d_out, int out_size, void* d_ws, size_t ws_size,
                              hipStream_t stream) {
    const float* emissions    = (const float*)d_in[0];
    const float* trans_params = (const float*)d_in[1];
    const int*   tags         = (const int*)d_in[2];
    const int*   who2who      = (const int*)d_in[3];
    const int*   intime       = (const int*)d_in[4];
    const int*   distance     = (const int*)d_in[5];
    float* out = (float*)d_out;

    float2* wsA = (float2*)d_ws;           // 8 MB
    float2* wsB = wsA + NM;                // 8 MB
    float2* wsC = wsB + NM;                // 8 MB   (24 MB total)

    crf_chunk<<<dim3(Bn), dim3(BLOCK), 0, stream>>>(
        emissions, trans_params, tags, who2who, intime, distance,
        wsA, wsB, wsC);
    crf_reduce<<<dim3(Bn / 4), dim3(BLOCK), 0, stream>>>(
        wsA, wsB, wsC, out);
}